// Round 10
// baseline (131.158 us; speedup 1.0000x reference)
//
#include <hip/hip_runtime.h>
#include <math.h>

// Problem constants (fixed by setup_inputs): B=8, C=4, H=W=64, K=8192
#define N_POINTS 32768   // B*H*W
#define KCODES   8192
#define HW       4096
#define CHW      16384
#define NSEG     64
#define SEGLEN   (KCODES / NSEG)   // 128 codes per segment
#define PPT      8                 // points per thread in vq_scan
#define QPT      (PPT / 2)         // point-pairs per thread (packed fp32)
#define PTILE    (256 * PPT)       // 2048 points per block

// ws layout (bytes): packed u64[32768] @ 0 — (sortable(best)<<32)|k per point
#define WS_PACKED 0

typedef float v2f __attribute__((ext_vector_type(2)));

// Bit-exact conv z = W x + b, numpy sequential c-order, no FMA contraction.
__device__ __forceinline__ void compute_z(
    const float* __restrict__ ze, const float* __restrict__ w,
    const float* __restrict__ bias, int n, float zo[4], float& zz) {
  int b = n >> 12, hw = n & 4095;
  const float* p = ze + b * CHW + hw;
  float x0 = p[0], x1 = p[HW], x2 = p[2 * HW], x3 = p[3 * HW];
#pragma unroll
  for (int o = 0; o < 4; ++o) {
    float acc = __fmul_rn(x0, w[o * 4 + 0]);
    acc = __fadd_rn(acc, __fmul_rn(x1, w[o * 4 + 1]));
    acc = __fadd_rn(acc, __fmul_rn(x2, w[o * 4 + 2]));
    acc = __fadd_rn(acc, __fmul_rn(x3, w[o * 4 + 3]));
    zo[o] = __fadd_rn(acc, bias[o]);
  }
  float s = __fmul_rn(zo[0], zo[0]);
  s = __fadd_rn(s, __fmul_rn(zo[1], zo[1]));
  s = __fadd_rn(s, __fmul_rn(zo[2], zo[2]));
  s = __fadd_rn(s, __fmul_rn(zo[3], zo[3]));
  zz = s;
}

// ---------------- Kernel S: fused conv + argmin scan, packed fp32 ----------
// R4-R9: scan pinned at ~60.5us across every structural variant; issue time
// equals the 12-op/pair scalar floor. Attack the op count: v_pk_mul/add_f32
// (VOP3P) processes 2 points/lane-op -> 9 fp ops serve 2 pairs (4.5/pair);
// cmp+2*cndmask per point remain scalar. ~7.5 ops/pair, floor 41 -> ~26us.
// contract(off): elementwise vector mul/add keep separate IEEE roundings ->
// bit-identical to the scalar __fmul_rn/__fadd_rn chain (proven absmax 0.0).
// Codebook segment staged+transformed in LDS directly from cb (vq_init gone);
// every block computes identical 2*c / |c|^2 bitwise (same op order).
__global__ __launch_bounds__(256, 3) void vq_scan(
    const float* __restrict__ ze, const float* __restrict__ w,
    const float* __restrict__ bias, const float* __restrict__ cb,
    unsigned long long* __restrict__ packed) {
#pragma clang fp contract(off)
  __shared__ float4 s_c[SEGLEN];            // 2*codebook segment (2048 B)
  __shared__ float  s_n[SEGLEN];            // |c|^2 segment (512 B)
  int tid = threadIdx.x;
  int k0 = blockIdx.y * SEGLEN;
  if (tid < SEGLEN) {
    float4 cv = ((const float4*)cb)[k0 + tid];
    // doubling by 2 is exact: sum(2*z*c) == 2*sum(z*c) bitwise
    s_c[tid] = make_float4(2.f * cv.x, 2.f * cv.y, 2.f * cv.z, 2.f * cv.w);
    float s = __fmul_rn(cv.x, cv.x);
    s = __fadd_rn(s, __fmul_rn(cv.y, cv.y));
    s = __fadd_rn(s, __fmul_rn(cv.z, cv.z));
    s = __fadd_rn(s, __fmul_rn(cv.w, cv.w));
    s_n[tid] = s;
  }
  // conv for this thread's 8 points while the staging loads land
  int n0 = blockIdx.x * PTILE + tid;        // points n0 + 256*p, coalesced
  v2f zp[4][QPT], zz2[QPT];
  float best[PPT];
  int bidx[PPT];
#pragma unroll
  for (int q = 0; q < QPT; ++q) {
    float za[4], zb[4], zza, zzb;
    compute_z(ze, w, bias, n0 + 256 * (2 * q + 0), za, zza);
    compute_z(ze, w, bias, n0 + 256 * (2 * q + 1), zb, zzb);
#pragma unroll
    for (int c = 0; c < 4; ++c) zp[c][q] = (v2f){za[c], zb[c]};
    zz2[q] = (v2f){zza, zzb};
    best[2 * q] = INFINITY; best[2 * q + 1] = INFINITY;
    bidx[2 * q] = 0; bidx[2 * q + 1] = 0;
  }
  __syncthreads();
  // ---- double-buffered chunk loop (4 codes/chunk, ascending k) ----
  float4 cA[4], nA;
  cA[0] = s_c[0]; cA[1] = s_c[1]; cA[2] = s_c[2]; cA[3] = s_c[3];
  nA = *(const float4*)&s_n[0];
  for (int kc = 0; kc < SEGLEN; kc += 4) {
    int kn = (kc + 4) & (SEGLEN - 1);       // wraps harmlessly on last iter
    float4 cB[4], nB;
    cB[0] = s_c[kn + 0]; cB[1] = s_c[kn + 1];
    cB[2] = s_c[kn + 2]; cB[3] = s_c[kn + 3];
    nB = *(const float4*)&s_n[kn];
    float cnr[4] = {nA.x, nA.y, nA.z, nA.w};
#pragma unroll
    for (int r = 0; r < 4; ++r) {
      int kk = k0 + kc + r;                 // ascending k: strict < = first-min
#pragma unroll
      for (int q = 0; q < QPT; ++q) {
        // 2*dot, numpy's sequential rounding order; scalar operands splat
        // across both halves (VOP3P broadcast). contract(off) -> no fma.
        v2f d = zp[0][q] * cA[r].x;
        d = d + zp[1][q] * cA[r].y;
        d = d + zp[2][q] * cA[r].z;
        d = d + zp[3][q] * cA[r].w;
        // ref: (|z|^2 - 2*dot) + |c|^2, left-to-right
        v2f s = (zz2[q] - d) + cnr[r];
        if (s.x < best[2 * q])     { best[2 * q] = s.x;     bidx[2 * q] = kk; }
        if (s.y < best[2 * q + 1]) { best[2 * q + 1] = s.y; bidx[2 * q + 1] = kk; }
      }
    }
    cA[0] = cB[0]; cA[1] = cB[1]; cA[2] = cB[2]; cA[3] = cB[3];
    nA = nB;
  }
#pragma unroll
  for (int p = 0; p < PPT; ++p) {
    // pack (sortable float, k): u64 min == (min value, then min k)
    unsigned int u = __float_as_uint(best[p]);
    unsigned int so = (u & 0x80000000u) ? ~u : (u | 0x80000000u);
    unsigned long long key =
        ((unsigned long long)so << 32) | (unsigned int)bidx[p];
    atomicMin(&packed[n0 + 256 * p], key);
  }
}

// ---------------- Kernel F: decode, gather, latent write, loss -------------
__global__ __launch_bounds__(256) void vq_finish(
    const float* __restrict__ ze, const float* __restrict__ w,
    const float* __restrict__ bias, const float* __restrict__ cb,
    const unsigned long long* __restrict__ packed, float* __restrict__ out) {
  int n = blockIdx.x * 256 + threadIdx.x;
  int bidx = (unsigned int)(packed[n] & 0xFFFFFFFFull);
  float4 c = ((const float4*)cb)[bidx];     // bit-exact gather (16B aligned)
  int b = n >> 12, hw = n & 4095;
  float* o = out + b * CHW + hw;
  o[0] = c.x; o[HW] = c.y; o[2 * HW] = c.z; o[3 * HW] = c.w;
  float z[4], zz;
  compute_z(ze, w, bias, n, z, zz);
  float d0 = c.x - z[0], d1 = c.y - z[1], d2 = c.z - z[2], d3 = c.w - z[3];
  float e = d0 * d0 + d1 * d1 + d2 * d2 + d3 * d3;
#pragma unroll
  for (int off = 32; off > 0; off >>= 1) e += __shfl_down(e, off, 64);
  __shared__ float sred[4];
  if ((threadIdx.x & 63) == 0) sred[threadIdx.x >> 6] = e;
  __syncthreads();
  if (threadIdx.x == 0) {
    float t = (sred[0] + sred[1]) + (sred[2] + sred[3]);
    // q_loss = (1 + BETA) * mean over 131072 elements
    atomicAdd(out + (N_POINTS * 4), t * (1.25f / 131072.f));
  }
}

extern "C" void kernel_launch(void* const* d_in, const int* in_sizes, int n_in,
                              void* d_out, int out_size, void* d_ws, size_t ws_size,
                              hipStream_t stream) {
  const float* ze   = (const float*)d_in[0];  // z_e_in [8,4,64,64]
  const float* w    = (const float*)d_in[1];  // pq_w [4,4]
  const float* bias = (const float*)d_in[2];  // pq_b [4]
  const float* cb   = (const float*)d_in[3];  // codebook [8192,4]

  unsigned long long* packed = (unsigned long long*)((char*)d_ws + WS_PACKED);
  float* out = (float*)d_out;

  // packed := all-ones (atomicMin identity); loss slot := 0
  hipMemsetAsync(packed, 0xFF, (size_t)N_POINTS * 8, stream);
  hipMemsetAsync(out + (N_POINTS * 4), 0, sizeof(float), stream);

  vq_scan<<<dim3(N_POINTS / PTILE, NSEG), 256, 0, stream>>>(
      ze, w, bias, cb, packed);
  vq_finish<<<128, 256, 0, stream>>>(ze, w, bias, cb, packed, out);
}